// Round 8
// baseline (273.034 us; speedup 1.0000x reference)
//
#include <hip/hip_runtime.h>
#include <hip/hip_cooperative_groups.h>

namespace cg = cooperative_groups;

// Problem constants
#define LSEQ 1024
#define DMODEL 1024
#define NHEADS 16
#define FDIM 16
#define HDIM 64
#define CHUNK 64
#define NCHUNK 16

typedef __attribute__((ext_vector_type(8))) short short8;   // 8 bf16 (4 VGPRs)
typedef __attribute__((ext_vector_type(4))) float floatx4;  // MFMA acc

__device__ __forceinline__ float bf2f(unsigned short u) {
    unsigned int x = ((unsigned int)u) << 16;
    return __builtin_bit_cast(float, x);
}
__device__ __forceinline__ unsigned short f2bf(float f) {
    unsigned int x = __builtin_bit_cast(unsigned int, f);
    unsigned int r = (x + 0x7fffu + ((x >> 16) & 1u)) >> 16;
    return (unsigned short)r;
}

// Workspace layout (ushort indices):
//   qbB @0        (262144)   bf16 q  [1024][256]
//   kbB @262144   (262144)   bf16 k  [1024][256]
//   vbB @524288   (1048576)  bf16 v  [1024][1024]
//   ybB @1572864  (1048576)  bf16 y  [1024][1024]
#define U_QB   0
#define U_KB   262144
#define U_VB   524288
#define U_YB   1572864

#define MFMA(a, b, c) __builtin_amdgcn_mfma_f32_16x16x32_bf16((a), (b), (c), 0, 0, 0)

// LDS union across phases (34816 B max -> 1+ blocks/CU co-resident)
struct SMemGemm { unsigned short As[64][136]; unsigned short Bs[64][136]; };
struct SMemFA {
    unsigned short qs[64][40];
    unsigned short ksm[64][40];
    unsigned short vT[80][72];
    unsigned short P[64][72];
};
union SMemU { SMemGemm g; SMemFA f; };

// ---------------------------------------------------------------------------
// Pipelined 64x64 GEMM tile body: C(64x64) = A[arow0:+64] @ B[brow0:+64]^T,
// both lda = 1024, K = 1024, BK = 128. Loads for iter k+1 issue after the
// LDS-ready barrier so they overlap the 16 MFMAs (vmcnt drain deferred).
// acc order: 00,01,10,11 (mi*2+ni).
// ---------------------------------------------------------------------------
__device__ __forceinline__ void gemm64_body(
    SMemGemm& s, const void* Araw, int a_fp32, int arow0,
    const void* Braw, int b_fp32, int brow0, floatx4 acc[4]) {
    int t = threadIdx.x;
    int r = t >> 2, c0 = (t & 3) * 32;
    int wave = t >> 6, lane = t & 63;
    int ml = lane & 15, q4 = lane >> 4;
    int mq = (wave >> 1) * 32, nq = (wave & 1) * 32;
    #pragma unroll
    for (int i = 0; i < 4; ++i) acc[i] = (floatx4){0.f, 0.f, 0.f, 0.f};

    short8 av[4], bv[4], av2[4], bv2[4];
    auto stage = [&](int k0, short8* a, short8* b) {
        if (!a_fp32) {
            const unsigned short* Ap = (const unsigned short*)Araw + (size_t)(arow0 + r) * DMODEL + k0 + c0;
            #pragma unroll
            for (int j = 0; j < 4; ++j) a[j] = *(const short8*)(Ap + j * 8);
        } else {
            const float* Ap = (const float*)Araw + (size_t)(arow0 + r) * DMODEL + k0 + c0;
            #pragma unroll
            for (int j = 0; j < 4; ++j)
                #pragma unroll
                for (int u = 0; u < 8; ++u) a[j][u] = (short)f2bf(Ap[j * 8 + u]);
        }
        if (!b_fp32) {
            const unsigned short* Bp = (const unsigned short*)Braw + (size_t)(brow0 + r) * DMODEL + k0 + c0;
            #pragma unroll
            for (int j = 0; j < 4; ++j) b[j] = *(const short8*)(Bp + j * 8);
        } else {
            const float* Bp = (const float*)Braw + (size_t)(brow0 + r) * DMODEL + k0 + c0;
            #pragma unroll
            for (int j = 0; j < 4; ++j)
                #pragma unroll
                for (int u = 0; u < 8; ++u) b[j][u] = (short)f2bf(Bp[j * 8 + u]);
        }
    };

    stage(0, av, bv);
    for (int k0 = 0; k0 < DMODEL; k0 += 128) {
        __syncthreads();   // previous iter's LDS reads done
        #pragma unroll
        for (int j = 0; j < 4; ++j) {
            *(short8*)&s.As[r][c0 + j * 8] = av[j];
            *(short8*)&s.Bs[r][c0 + j * 8] = bv[j];
        }
        __syncthreads();   // LDS ready
        if (k0 + 128 < DMODEL) stage(k0 + 128, av2, bv2);   // overlap with MFMA
        #pragma unroll
        for (int kk = 0; kk < 4; ++kk) {
            short8 a0 = *(const short8*)&s.As[mq + ml][kk * 32 + q4 * 8];
            short8 a1 = *(const short8*)&s.As[mq + 16 + ml][kk * 32 + q4 * 8];
            short8 b0 = *(const short8*)&s.Bs[nq + ml][kk * 32 + q4 * 8];
            short8 b1 = *(const short8*)&s.Bs[nq + 16 + ml][kk * 32 + q4 * 8];
            acc[0] = MFMA(a0, b0, acc[0]); acc[1] = MFMA(a0, b1, acc[1]);
            acc[2] = MFMA(a1, b0, acc[2]); acc[3] = MFMA(a1, b1, acc[3]);
        }
        #pragma unroll
        for (int j = 0; j < 4; ++j) { av[j] = av2[j]; bv[j] = bv2[j]; }
    }
    __syncthreads();   // LDS free for next use
}

// ---------------------------------------------------------------------------
// The cooperative mega-kernel: phase A (qkv GEMM, 384 tiles over 256 blocks)
// -> grid.sync -> phase B (flash quadratic attention, 1 job/block)
// -> grid.sync -> phase C (out GEMM, 1 tile/block).
// ---------------------------------------------------------------------------
__global__ __launch_bounds__(256) void mega(
    const void* __restrict__ hidR, const void* __restrict__ WqR,
    const void* __restrict__ WkR, const void* __restrict__ WvR,
    const void* __restrict__ WoR, void* __restrict__ outv,
    unsigned short* __restrict__ qb, unsigned short* __restrict__ kb,
    unsigned short* __restrict__ vb, unsigned short* __restrict__ ybB) {
    cg::grid_group grid = cg::this_grid();
    __shared__ __align__(16) SMemU sm;
    int bid = blockIdx.x;
    int t = threadIdx.x, lane = t & 63, wave = t >> 6;
    int ml = lane & 15, q4 = lane >> 4;

    // ---- dtype detection (uniform across blocks; L2-hot after first)
    int fp32;
    {
        __shared__ int cnt;
        if (t == 0) cnt = 0;
        __syncthreads();
        const unsigned short* wq = (const unsigned short*)WqR;
        int bad = 0;
        for (int i = t; i < 1024; i += 256) {
            int e = (wq[i] >> 7) & 0xFF;
            if (e >= 143 || (e > 0 && e <= 80)) bad++;
        }
        if (bad) atomicAdd(&cnt, bad);
        __syncthreads();
        fp32 = cnt > 128;
    }

    // ================= Phase A: QKV projection =================
    // 384 tiles (mb 0..15 x nb 0..23); block b does T = b (+256 if b < 128).
    for (int T = bid; T < 384; T += 256) {
        int mb = T / 24, nb = T % 24;
        const void* Braw; unsigned short* Cout; int ldc, col0, br0;
        if (nb < 4)      { Braw = WqR; br0 = nb * 64;       Cout = qb; ldc = 256;  col0 = nb * 64; }
        else if (nb < 8) { Braw = WkR; br0 = (nb - 4) * 64; Cout = kb; ldc = 256;  col0 = (nb - 4) * 64; }
        else             { Braw = WvR; br0 = (nb - 8) * 64; Cout = vb; ldc = 1024; col0 = (nb - 8) * 64; }
        floatx4 acc[4];
        gemm64_body(sm.g, hidR, fp32, mb * 64, Braw, fp32, br0, acc);
        int mq = (wave >> 1) * 32, nq = (wave & 1) * 32;
        #pragma unroll
        for (int mi = 0; mi < 2; ++mi)
            #pragma unroll
            for (int ni = 0; ni < 2; ++ni) {
                floatx4 a = acc[mi * 2 + ni];
                int nloc = nq + ni * 16 + ml;
                #pragma unroll
                for (int r4 = 0; r4 < 4; ++r4) {
                    int row = mb * 64 + mq + mi * 16 + q4 * 4 + r4;
                    Cout[(size_t)row * ldc + col0 + nloc] = f2bf(a[r4]);
                }
            }
    }
    __threadfence();
    grid.sync();

    // ================= Phase B: flash quadratic attention =================
    {
        unsigned short (&qs)[64][40]  = sm.f.qs;
        unsigned short (&ksm)[64][40] = sm.f.ksm;
        unsigned short (&vT)[80][72]  = sm.f.vT;
        unsigned short (&P)[64][72]   = sm.f.P;
        int h = bid & 15, c = bid >> 4;
        int l0 = c * CHUNK;
        int m0 = wave * 16;

        {
            int m = t >> 2, i4 = (t & 3) * 4;
            *(ushort4*)&qs[m][i4] = *(const ushort4*)&qb[(size_t)(l0 + m) * 256 + h * 16 + i4];
            ushort4 z = {0, 0, 0, 0};
            *(ushort4*)&qs[m][16 + i4]  = z;
            *(ushort4*)&ksm[m][16 + i4] = z;   // k pad, persists across tiles
        }
        if (t < 64) {
            vT[64][t] = 0x3F80;   // 1.0 bf16 (denominator row)
            #pragma unroll
            for (int i = 65; i < 80; ++i) vT[i][t] = 0;
        }

        floatx4 acc[5];
        #pragma unroll
        for (int i = 0; i < 5; ++i) acc[i] = (floatx4){0.f, 0.f, 0.f, 0.f};

        for (int j = 0; j <= c; ++j) {
            {
                int m = t >> 2, i4 = (t & 3) * 4;
                *(ushort4*)&ksm[m][i4] = *(const ushort4*)&kb[(size_t)(j * 64 + m) * 256 + h * 16 + i4];
                int cc = (t & 3) * 16;
                unsigned short tmp[16];
                #pragma unroll
                for (int u = 0; u < 4; ++u)
                    *(ushort4*)&tmp[u * 4] = *(const ushort4*)&vb[(size_t)(j * 64 + m) * 1024 + h * 64 + cc + u * 4];
                #pragma unroll
                for (int u = 0; u < 16; ++u) vT[cc + u][m] = tmp[u];
            }
            __syncthreads();   // staging visible

            short8 aq = *(const short8*)&qs[m0 + ml][q4 * 8];
            bool diag = (j == c);
            #pragma unroll
            for (int nt = 0; nt < 4; ++nt) {
                short8 bk = *(const short8*)&ksm[nt * 16 + ml][q4 * 8];
                floatx4 s4 = {0.f, 0.f, 0.f, 0.f};
                s4 = MFMA(aq, bk, s4);
                int tt = nt * 16 + ml;
                #pragma unroll
                for (int r = 0; r < 4; ++r) {
                    int lrow = m0 + q4 * 4 + r;
                    float s = s4[r];
                    float p = 1.f + 0.25f * s + 0.03125f * s * s;
                    if (diag && tt > lrow) p = 0.f;
                    P[lrow][tt] = f2bf(p);
                }
            }
            // P rows wave-private: no barrier needed before PV.
            #pragma unroll
            for (int k0 = 0; k0 < 64; k0 += 32) {
                short8 ap = *(const short8*)&P[m0 + ml][k0 + q4 * 8];
                #pragma unroll
                for (int nt = 0; nt < 5; ++nt) {
                    short8 bvv = *(const short8*)&vT[nt * 16 + ml][k0 + q4 * 8];
                    acc[nt] = MFMA(ap, bvv, acc[nt]);
                }
            }
            __syncthreads();   // protect ksm/vT from next tile's staging
        }

        #pragma unroll
        for (int r = 0; r < 4; ++r) {
            float den = __shfl(acc[4][r], q4 * 16) + 1e-12f;
            float dinv = 1.f / den;
            int lrow = m0 + q4 * 4 + r;
            unsigned short* yp = ybB + (size_t)(l0 + lrow) * 1024 + h * 64;
            #pragma unroll
            for (int nt = 0; nt < 4; ++nt)
                yp[nt * 16 + ml] = f2bf(acc[nt][r] * dinv);
        }
    }
    __threadfence();
    grid.sync();

    // ================= Phase C: output projection =================
    {
        int nb = bid & 15, mb = bid >> 4;
        floatx4 acc[4];
        gemm64_body(sm.g, ybB, 0, mb * 64, WoR, fp32, nb * 64, acc);
        int mq = (wave >> 1) * 32, nq = (wave & 1) * 32;
        #pragma unroll
        for (int mi = 0; mi < 2; ++mi)
            #pragma unroll
            for (int ni = 0; ni < 2; ++ni) {
                floatx4 a = acc[mi * 2 + ni];
                int n = nb * 64 + nq + ni * 16 + ml;
                #pragma unroll
                for (int r4 = 0; r4 < 4; ++r4) {
                    int row = mb * 64 + mq + mi * 16 + q4 * 4 + r4;
                    size_t idx = (size_t)row * 1024 + n;
                    if (fp32) ((float*)outv)[idx] = a[r4];
                    else      ((unsigned short*)outv)[idx] = f2bf(a[r4]);
                }
            }
    }
}

// ---------------------------------------------------------------------------
extern "C" void kernel_launch(void* const* d_in, const int* in_sizes, int n_in,
                              void* d_out, int out_size, void* d_ws, size_t ws_size,
                              hipStream_t stream) {
    unsigned short* us = (unsigned short*)d_ws;
    unsigned short* qbB = us + U_QB;
    unsigned short* kbB = us + U_KB;
    unsigned short* vbB = us + U_VB;
    unsigned short* ybB = us + U_YB;
    size_t need = (size_t)(U_YB + 1048576) * 2ull;
    if (ws_size < need) return;

    const void* hid = d_in[0];
    const void* wq  = d_in[1];
    const void* wk  = d_in[2];
    const void* wv  = d_in[3];
    const void* wo  = d_in[4];
    void* outp = d_out;
    void* kargs[] = { (void*)&hid, (void*)&wq, (void*)&wk, (void*)&wv, (void*)&wo,
                      (void*)&outp, (void*)&qbB, (void*)&kbB, (void*)&vbB, (void*)&ybB };
    hipLaunchCooperativeKernel((const void*)mega, dim3(256), dim3(256), kargs, 0, stream);
}

// Round 9
// 140.460 us; speedup vs baseline: 1.9439x; 1.9439x over previous
//
#include <hip/hip_runtime.h>

// Problem constants
#define LSEQ 1024
#define DMODEL 1024
#define NHEADS 16
#define FDIM 16
#define HDIM 64
#define CHUNK 64
#define NCHUNK 16

typedef __attribute__((ext_vector_type(8))) short short8;   // 8 bf16 (4 VGPRs)
typedef __attribute__((ext_vector_type(4))) float floatx4;  // MFMA acc

__device__ __forceinline__ float bf2f(unsigned short u) {
    unsigned int x = ((unsigned int)u) << 16;
    return __builtin_bit_cast(float, x);
}
__device__ __forceinline__ unsigned short f2bf(float f) {
    unsigned int x = __builtin_bit_cast(unsigned int, f);
    unsigned int r = (x + 0x7fffu + ((x >> 16) & 1u)) >> 16;
    return (unsigned short)r;
}

// Per-block dtype detector: samples 1024 ushorts of Wq. bf16 data -> exponents
// cluster tightly (bad ~0%); fp32-as-ushort -> half the samples are uniform
// mantissa bits (bad ~30%+). Returns 1 if inputs are fp32.
__device__ __forceinline__ int block_detect_fp32(const unsigned short* wq) {
    __shared__ int cnt;
    if (threadIdx.x == 0) cnt = 0;
    __syncthreads();
    int bad = 0;
    for (int i = threadIdx.x; i < 1024; i += blockDim.x) {
        int e = (wq[i] >> 7) & 0xFF;
        if (e >= 143 || (e > 0 && e <= 80)) bad++;
    }
    if (bad) atomicAdd(&cnt, bad);
    __syncthreads();
    return cnt > 128;
}

// Workspace layout (ushort indices):
//   qbB @0        (262144)   bf16 q  [1024][256]
//   kbB @262144   (262144)   bf16 k  [1024][256]
//   vbB @524288   (1048576)  bf16 v  [1024][1024]
//   ybB @1572864  (1048576)  bf16 y  [1024][1024]
#define U_QB   0
#define U_KB   262144
#define U_VB   524288
#define U_YB   1572864

#define MFMA(a, b, c) __builtin_amdgcn_mfma_f32_16x16x32_bf16((a), (b), (c), 0, 0, 0)

// ---------------------------------------------------------------------------
// Pipelined 64x64 GEMM tile body: C(64x64) = A[arow0:+64] @ B[brow0:+64]^T,
// lda = ldb = 1024, K = 1024, BK = 128. Iter k+1's global loads issue right
// after the LDS-ready barrier, overlapping the 16 MFMAs; the vmcnt drain
// lands at the NEXT iteration's LDS write instead of serializing each iter.
// acc order: 00,01,10,11 (mi*2+ni).
// ---------------------------------------------------------------------------
__device__ __forceinline__ void gemm64_body(
    unsigned short (&As)[64][136], unsigned short (&Bs)[64][136],
    const void* Araw, int a_fp32, int arow0,
    const void* Braw, int b_fp32, int brow0, floatx4 acc[4]) {
    int t = threadIdx.x;
    int r = t >> 2, c0 = (t & 3) * 32;
    int wave = t >> 6, lane = t & 63;
    int ml = lane & 15, q4 = lane >> 4;
    int mq = (wave >> 1) * 32, nq = (wave & 1) * 32;
    #pragma unroll
    for (int i = 0; i < 4; ++i) acc[i] = (floatx4){0.f, 0.f, 0.f, 0.f};

    short8 av[4], bv[4], av2[4], bv2[4];
    auto stage = [&](int k0, short8* a, short8* b) {
        if (!a_fp32) {
            const unsigned short* Ap = (const unsigned short*)Araw + (size_t)(arow0 + r) * DMODEL + k0 + c0;
            #pragma unroll
            for (int j = 0; j < 4; ++j) a[j] = *(const short8*)(Ap + j * 8);
        } else {
            const float* Ap = (const float*)Araw + (size_t)(arow0 + r) * DMODEL + k0 + c0;
            #pragma unroll
            for (int j = 0; j < 4; ++j)
                #pragma unroll
                for (int u = 0; u < 8; ++u) a[j][u] = (short)f2bf(Ap[j * 8 + u]);
        }
        if (!b_fp32) {
            const unsigned short* Bp = (const unsigned short*)Braw + (size_t)(brow0 + r) * DMODEL + k0 + c0;
            #pragma unroll
            for (int j = 0; j < 4; ++j) b[j] = *(const short8*)(Bp + j * 8);
        } else {
            const float* Bp = (const float*)Braw + (size_t)(brow0 + r) * DMODEL + k0 + c0;
            #pragma unroll
            for (int j = 0; j < 4; ++j)
                #pragma unroll
                for (int u = 0; u < 8; ++u) b[j][u] = (short)f2bf(Bp[j * 8 + u]);
        }
    };

    stage(0, av, bv);
    for (int k0 = 0; k0 < DMODEL; k0 += 128) {
        __syncthreads();   // previous iter's LDS reads done
        #pragma unroll
        for (int j = 0; j < 4; ++j) {
            *(short8*)&As[r][c0 + j * 8] = av[j];
            *(short8*)&Bs[r][c0 + j * 8] = bv[j];
        }
        __syncthreads();   // LDS ready
        if (k0 + 128 < DMODEL) stage(k0 + 128, av2, bv2);   // overlap with MFMA
        #pragma unroll
        for (int kk = 0; kk < 4; ++kk) {
            short8 a0 = *(const short8*)&As[mq + ml][kk * 32 + q4 * 8];
            short8 a1 = *(const short8*)&As[mq + 16 + ml][kk * 32 + q4 * 8];
            short8 b0 = *(const short8*)&Bs[nq + ml][kk * 32 + q4 * 8];
            short8 b1 = *(const short8*)&Bs[nq + 16 + ml][kk * 32 + q4 * 8];
            acc[0] = MFMA(a0, b0, acc[0]); acc[1] = MFMA(a0, b1, acc[1]);
            acc[2] = MFMA(a1, b0, acc[2]); acc[3] = MFMA(a1, b1, acc[3]);
        }
        #pragma unroll
        for (int j = 0; j < 4; ++j) { av[j] = av2[j]; bv[j] = bv2[j]; }
    }
}

// ---------------------------------------------------------------------------
// Kernel 1: QKV projection. grid (24, 16): nb 0..3 q, 4..7 k, 8..23 v.
// ---------------------------------------------------------------------------
__global__ __launch_bounds__(256) void qkv_gemm(
    const void* __restrict__ hidR, const void* __restrict__ WqR,
    const void* __restrict__ WkR, const void* __restrict__ WvR,
    unsigned short* __restrict__ qb, unsigned short* __restrict__ kb,
    unsigned short* __restrict__ vb) {
    int fp32 = block_detect_fp32((const unsigned short*)WqR);
    __shared__ __align__(16) unsigned short As[64][136];
    __shared__ __align__(16) unsigned short Bs[64][136];
    int nb = blockIdx.x, mb = blockIdx.y;
    const void* Braw; unsigned short* Cout; int ldc, col0, br0;
    if (nb < 4)      { Braw = WqR; br0 = nb * 64;       Cout = qb; ldc = 256;  col0 = nb * 64; }
    else if (nb < 8) { Braw = WkR; br0 = (nb - 4) * 64; Cout = kb; ldc = 256;  col0 = (nb - 4) * 64; }
    else             { Braw = WvR; br0 = (nb - 8) * 64; Cout = vb; ldc = 1024; col0 = (nb - 8) * 64; }

    floatx4 acc[4];
    gemm64_body(As, Bs, hidR, fp32, mb * 64, Braw, fp32, br0, acc);

    int wave = threadIdx.x >> 6, lane = threadIdx.x & 63;
    int ml = lane & 15, q4 = lane >> 4;
    int mq = (wave >> 1) * 32, nq = (wave & 1) * 32;
    #pragma unroll
    for (int mi = 0; mi < 2; ++mi)
        #pragma unroll
        for (int ni = 0; ni < 2; ++ni) {
            floatx4 a = acc[mi * 2 + ni];
            int nloc = nq + ni * 16 + ml;
            #pragma unroll
            for (int r4 = 0; r4 < 4; ++r4) {
                int row = mb * 64 + mq + mi * 16 + q4 * 4 + r4;
                Cout[(size_t)row * ldc + col0 + nloc] = f2bf(a[r4]);
            }
        }
}

// ---------------------------------------------------------------------------
// Kernel 2: flash-style quadratic polynomial attention with k/v prefetch.
// S(l,t) = 1 + (q.k)/4 + (q.k)^2/32, causal; y = S V / (S 1).
// Block (h, c): Q rows [64c, +64), loop kv tiles j = 0..c. Next tile's k/v
// loads issue right after the staging barrier, overlapping S/PV MFMAs.
// ---------------------------------------------------------------------------
__global__ __launch_bounds__(256) void flash_attn(
    const unsigned short* __restrict__ qb, const unsigned short* __restrict__ kb,
    const unsigned short* __restrict__ vb, unsigned short* __restrict__ ybB) {
    int h = blockIdx.x & 15, c = blockIdx.x >> 4;
    int l0 = c * CHUNK;
    __shared__ __align__(16) unsigned short qs[64][40];
    __shared__ __align__(16) unsigned short ksm[64][40];
    __shared__ __align__(16) unsigned short vT[80][72];   // rows 0..63 v^T, 64 ones
    __shared__ __align__(16) unsigned short P[64][72];
    int t = threadIdx.x, lane = t & 63, wave = t >> 6;
    int ml = lane & 15, q4 = lane >> 4;
    int m0 = wave * 16;
    int sm = t >> 2, si4 = (t & 3) * 4, scc = (t & 3) * 16;

    // ---- one-time staging: q rows (zero-padded K=32), vT pad rows
    {
        *(ushort4*)&qs[sm][si4] = *(const ushort4*)&qb[(size_t)(l0 + sm) * 256 + h * 16 + si4];
        ushort4 z = {0, 0, 0, 0};
        *(ushort4*)&qs[sm][16 + si4]  = z;
        *(ushort4*)&ksm[sm][16 + si4] = z;   // k pad, persists across tiles
    }
    if (t < 64) {
        vT[64][t] = 0x3F80;   // 1.0 bf16 (denominator row)
        #pragma unroll
        for (int i = 65; i < 80; ++i) vT[i][t] = 0;
    }

    auto load_kv = [&](int j, ushort4& kr, ushort4 vr[4]) {
        kr = *(const ushort4*)&kb[(size_t)(j * 64 + sm) * 256 + h * 16 + si4];
        #pragma unroll
        for (int u = 0; u < 4; ++u)
            vr[u] = *(const ushort4*)&vb[(size_t)(j * 64 + sm) * 1024 + h * 64 + scc + u * 4];
    };

    floatx4 acc[5];
    #pragma unroll
    for (int i = 0; i < 5; ++i) acc[i] = (floatx4){0.f, 0.f, 0.f, 0.f};

    ushort4 kr, vr[4], kr2, vr2[4];
    load_kv(0, kr, vr);

    for (int j = 0; j <= c; ++j) {
        // ---- write prefetched k_j / v_j^T to LDS
        {
            *(ushort4*)&ksm[sm][si4] = kr;
            unsigned short tmp[16];
            #pragma unroll
            for (int u = 0; u < 4; ++u) *(ushort4*)&tmp[u * 4] = vr[u];
            #pragma unroll
            for (int u = 0; u < 16; ++u) vT[scc + u][sm] = tmp[u];
        }
        __syncthreads();   // staging visible (also covers qs on first iter)
        if (j < c) load_kv(j + 1, kr2, vr2);   // overlap with MFMAs below

        // ---- scores S = q k^T (K=32, zero-padded), poly + causal -> P
        short8 aq = *(const short8*)&qs[m0 + ml][q4 * 8];
        bool diag = (j == c);
        #pragma unroll
        for (int nt = 0; nt < 4; ++nt) {
            short8 bk = *(const short8*)&ksm[nt * 16 + ml][q4 * 8];
            floatx4 s4 = {0.f, 0.f, 0.f, 0.f};
            s4 = MFMA(aq, bk, s4);
            int tt = nt * 16 + ml;
            #pragma unroll
            for (int r = 0; r < 4; ++r) {
                int lrow = m0 + q4 * 4 + r;
                float s = s4[r];
                float p = 1.f + 0.25f * s + 0.03125f * s * s;
                if (diag && tt > lrow) p = 0.f;
                P[lrow][tt] = f2bf(p);
            }
        }
        // P rows are wave-private (written rows m0..m0+15, read rows m0+ml):
        // no barrier needed before PV.

        // ---- PV: acc[nt] += P x vT (nt=4 ones-row -> denominator)
        #pragma unroll
        for (int k0 = 0; k0 < 64; k0 += 32) {
            short8 ap = *(const short8*)&P[m0 + ml][k0 + q4 * 8];
            #pragma unroll
            for (int nt = 0; nt < 5; ++nt) {
                short8 bvv = *(const short8*)&vT[nt * 16 + ml][k0 + q4 * 8];
                acc[nt] = MFMA(ap, bvv, acc[nt]);
            }
        }
        __syncthreads();   // protect ksm/vT from next tile's staging
        kr = kr2;
        #pragma unroll
        for (int u = 0; u < 4; ++u) vr[u] = vr2[u];
    }

    // ---- epilogue: den broadcast via shfl; y = num/den -> bf16
    #pragma unroll
    for (int r = 0; r < 4; ++r) {
        float den = __shfl(acc[4][r], q4 * 16) + 1e-12f;
        float dinv = 1.f / den;
        int lrow = m0 + q4 * 4 + r;
        unsigned short* yp = ybB + (size_t)(l0 + lrow) * 1024 + h * 64;
        #pragma unroll
        for (int nt = 0; nt < 4; ++nt)
            yp[nt * 16 + ml] = f2bf(acc[nt][r] * dinv);
    }
}

// ---------------------------------------------------------------------------
// Kernel 3: output projection. out = y @ Wo^T (1024^3). Output dtype per
// detector.
// ---------------------------------------------------------------------------
__global__ __launch_bounds__(256) void out_gemm(
    const unsigned short* __restrict__ A, const void* __restrict__ WoR,
    void* __restrict__ outv, const unsigned short* __restrict__ wqraw) {
    int fp32 = block_detect_fp32(wqraw);
    __shared__ __align__(16) unsigned short As[64][136];
    __shared__ __align__(16) unsigned short Bs[64][136];
    int nb = blockIdx.x, mb = blockIdx.y;

    floatx4 acc[4];
    gemm64_body(As, Bs, A, 0, mb * 64, WoR, fp32, nb * 64, acc);

    int wave = threadIdx.x >> 6, lane = threadIdx.x & 63;
    int ml = lane & 15, q4 = lane >> 4;
    int mq = (wave >> 1) * 32, nq = (wave & 1) * 32;
    #pragma unroll
    for (int mi = 0; mi < 2; ++mi)
        #pragma unroll
        for (int ni = 0; ni < 2; ++ni) {
            floatx4 a = acc[mi * 2 + ni];
            int n = nb * 64 + nq + ni * 16 + ml;
            #pragma unroll
            for (int r4 = 0; r4 < 4; ++r4) {
                int row = mb * 64 + mq + mi * 16 + q4 * 4 + r4;
                size_t idx = (size_t)row * 1024 + n;
                if (fp32) ((float*)outv)[idx] = a[r4];
                else      ((unsigned short*)outv)[idx] = f2bf(a[r4]);
            }
        }
}

// ---------------------------------------------------------------------------
extern "C" void kernel_launch(void* const* d_in, const int* in_sizes, int n_in,
                              void* d_out, int out_size, void* d_ws, size_t ws_size,
                              hipStream_t stream) {
    unsigned short* us = (unsigned short*)d_ws;
    unsigned short* qbB = us + U_QB;
    unsigned short* kbB = us + U_KB;
    unsigned short* vbB = us + U_VB;
    unsigned short* ybB = us + U_YB;
    size_t need = (size_t)(U_YB + 1048576) * 2ull;
    if (ws_size < need) return;

    qkv_gemm<<<dim3(24, 16), 256, 0, stream>>>(d_in[0], d_in[1], d_in[2], d_in[3], qbB, kbB, vbB);
    flash_attn<<<dim3(256), 256, 0, stream>>>(qbB, kbB, vbB, ybB);
    out_gemm<<<dim3(16, 16), 256, 0, stream>>>(ybB, d_in[4], d_out, (const unsigned short*)d_in[1]);
}